// Round 1
// baseline (36865.002 us; speedup 1.0000x reference)
//
#include <hip/hip_runtime.h>
#include <math.h>

#define BS 32
#define M 64
#define NMAT 2048      // BS*M
#define DIN 100
#define DOUT 64
#define DD 4096        // DOUT*DOUT
#define EPSV 1e-6f
#define NSWEEP 9

// ---------------- transform: S = W^T X W for each of q,k,v ----------------
__global__ __launch_bounds__(256) void transform_kernel(
    const float* __restrict__ x,
    const float* __restrict__ Wq, const float* __restrict__ Wk, const float* __restrict__ Wv,
    float* __restrict__ Qo, float* __restrict__ Ko, float* __restrict__ Vo)
{
    __shared__ float Xs[DIN][DIN + 1];      // 100x101
    __shared__ float Ws[DIN][DOUT + 1];     // 100x65
    __shared__ float Ts[DIN][DOUT + 1];     // 100x65
    const int n = blockIdx.x;
    const int t = threadIdx.x;
    const float* Xp = x + (size_t)n * DIN * DIN;
    for (int idx = t; idx < DIN * DIN; idx += 256)
        Xs[idx / DIN][idx % DIN] = Xp[idx];

    const float* Wlist[3] = {Wq, Wk, Wv};
    float* Olist[3] = {Qo, Ko, Vo};
    const int tj = t & 63;   // 0..63
    const int tp = t >> 6;   // 0..3

    for (int w = 0; w < 3; ++w) {
        __syncthreads();     // Xs ready (w=0); Ws/Ts free (w>0)
        const float* W = Wlist[w];
        for (int idx = t; idx < DIN * DOUT; idx += 256)
            Ws[idx / DOUT][idx % DOUT] = W[idx];
        __syncthreads();
        // T = X * W : thread computes T[p][tj] for p = tp + 4*pi
        float acc[25];
        #pragma unroll
        for (int i = 0; i < 25; ++i) acc[i] = 0.f;
        for (int qq = 0; qq < DIN; ++qq) {
            float wv = Ws[qq][tj];
            #pragma unroll
            for (int pi = 0; pi < 25; ++pi)
                acc[pi] += Xs[tp + 4 * pi][qq] * wv;
        }
        #pragma unroll
        for (int pi = 0; pi < 25; ++pi)
            Ts[tp + 4 * pi][tj] = acc[pi];
        __syncthreads();
        // S = W^T * T : thread computes S[i][tj] for i = tp + 4*ii
        float sacc[16];
        #pragma unroll
        for (int i = 0; i < 16; ++i) sacc[i] = 0.f;
        for (int p = 0; p < DIN; ++p) {
            float tv = Ts[p][tj];
            #pragma unroll
            for (int ii = 0; ii < 16; ++ii)
                sacc[ii] += Ws[p][tp + 4 * ii] * tv;
        }
        float* Op = Olist[w] + (size_t)n * DD;
        #pragma unroll
        for (int ii = 0; ii < 16; ++ii)
            Op[(tp + 4 * ii) * DOUT + tj] = sacc[ii];
    }
}

// ---------------- batched symmetric Jacobi eigendecomposition + f(A) ------
// MODE 0: out = U log(|L|+eps) U^T, optional Frobenius-norm output
// MODE 1: out = U exp(L) U^T
template <int MODE>
__global__ __launch_bounds__(256) void jacobi_kernel(
    const float* __restrict__ in, float* __restrict__ out, float* __restrict__ norms)
{
    __shared__ float As[DOUT][DOUT + 1];
    __shared__ float Vs[DOUT][DOUT + 1];
    __shared__ float pc[32], ps[32];
    __shared__ int ppi[32], pqi[32];
    __shared__ float fv[DOUT];
    const int t = threadIdx.x;
    const float* Ap = in + (size_t)blockIdx.x * DD;
    float* Gp = out + (size_t)blockIdx.x * DD;

    for (int idx = t; idx < DD; idx += 256) {
        int r = idx >> 6, c = idx & 63;
        As[r][c] = Ap[idx];
        Vs[r][c] = (r == c) ? 1.f : 0.f;
    }
    __syncthreads();

    for (int sw = 0; sw < NSWEEP; ++sw) {
        for (int rr = 0; rr < 63; ++rr) {
            // 32 disjoint rotation pairs (round-robin / circle ordering)
            if (t < 32) {
                int a, b;
                if (t == 0) { a = 63; b = rr; }
                else { a = (rr + t) % 63; b = (rr - t + 63) % 63; }
                int p = min(a, b), q = max(a, b);
                float app = As[p][p], aqq = As[q][q], apq = As[p][q];
                float c, s;
                if (fabsf(apq) > 1e-30f) {
                    float theta = (aqq - app) / (2.f * apq);
                    float tt = 1.f / (fabsf(theta) + sqrtf(1.f + theta * theta));
                    if (theta < 0.f) tt = -tt;
                    c = rsqrtf(1.f + tt * tt);
                    s = tt * c;
                } else { c = 1.f; s = 0.f; }
                pc[t] = c; ps[t] = s; ppi[t] = p; pqi[t] = q;
            }
            __syncthreads();
            // column update: A <- A*J, V <- V*J  (4096 tasks)
            #pragma unroll
            for (int u = 0; u < 16; ++u) {
                int task = t + 256 * u;
                int r = task & 63;
                int k = (task >> 6) & 31;
                int w = task >> 11;
                float c = pc[k], s = ps[k];
                int p = ppi[k], q = pqi[k];
                if (w == 0) {
                    float mp = As[r][p], mq = As[r][q];
                    As[r][p] = c * mp - s * mq;
                    As[r][q] = s * mp + c * mq;
                } else {
                    float mp = Vs[r][p], mq = Vs[r][q];
                    Vs[r][p] = c * mp - s * mq;
                    Vs[r][q] = s * mp + c * mq;
                }
            }
            __syncthreads();
            // row update: A <- J^T*A  (2048 tasks)
            #pragma unroll
            for (int u = 0; u < 8; ++u) {
                int task = t + 256 * u;
                int ci = task & 63;
                int k = task >> 6;
                float c = pc[k], s = ps[k];
                int p = ppi[k], q = pqi[k];
                float ap = As[p][ci], aq = As[q][ci];
                As[p][ci] = c * ap - s * aq;
                As[q][ci] = s * ap + c * aq;
            }
            __syncthreads();
        }
    }

    // eigenvalues on diag; apply f
    if (t < 64) {
        float lam = As[t][t];
        fv[t] = (MODE == 0) ? logf(fabsf(lam) + EPSV) : expf(lam);
    }
    __syncthreads();
    if (MODE == 0 && norms != nullptr && t == 0) {
        float nrm = 0.f;
        for (int k = 0; k < 64; ++k) nrm += fv[k] * fv[k];
        norms[blockIdx.x] = nrm;   // ||f(A)||_F^2 via orthogonality of V
    }
    // B = V * diag(f)  (into As)
    for (int idx = t; idx < DD; idx += 256) {
        int r = idx >> 6, c = idx & 63;
        As[r][c] = Vs[r][c] * fv[c];
    }
    __syncthreads();
    // G = B * V^T
    #pragma unroll
    for (int u = 0; u < 16; ++u) {
        int idx = t + 256 * u;
        int i = idx >> 6, j = idx & 63;
        float acc = 0.f;
        for (int k = 0; k < 64; ++k)
            acc += As[i][k] * Vs[j][k];
        Gp[idx] = acc;
    }
}

// ---------------- scores + softmax (per batch) ----------------------------
// cross[i][j] = <kf_i, qf_j>; scores = 1/(1+log1p(dist2+64*eps));
// prob[b][j][i] = softmax_i(scores[i][j])
__global__ __launch_bounds__(256) void scores_kernel(
    const float* __restrict__ logK, const float* __restrict__ logQ,
    const float* __restrict__ kn, const float* __restrict__ qn,
    float* __restrict__ prob)
{
    __shared__ float kf_t[64][65];
    __shared__ float qf_t[64][65];
    __shared__ float sc[64][65];
    __shared__ float mx[64], sm[64];
    const int b = blockIdx.x;
    const int t = threadIdx.x;
    const int ti = t >> 4, tjj = t & 15;
    float acc[4][4];
    #pragma unroll
    for (int di = 0; di < 4; ++di)
        #pragma unroll
        for (int dj = 0; dj < 4; ++dj) acc[di][dj] = 0.f;

    const float* Kb = logK + (size_t)b * M * DD;
    const float* Qb = logQ + (size_t)b * M * DD;
    for (int cf = 0; cf < DD; cf += 64) {
        __syncthreads();
        for (int idx = t; idx < 64 * 64; idx += 256) {
            int r = idx >> 6, c = idx & 63;
            kf_t[r][c] = Kb[(size_t)r * DD + cf + c];
            qf_t[r][c] = Qb[(size_t)r * DD + cf + c];
        }
        __syncthreads();
        for (int f = 0; f < 64; ++f) {
            float kv[4], qv[4];
            #pragma unroll
            for (int d = 0; d < 4; ++d) { kv[d] = kf_t[4 * ti + d][f]; qv[d] = qf_t[4 * tjj + d][f]; }
            #pragma unroll
            for (int di = 0; di < 4; ++di)
                #pragma unroll
                for (int dj = 0; dj < 4; ++dj)
                    acc[di][dj] += kv[di] * qv[dj];
        }
    }
    __syncthreads();
    #pragma unroll
    for (int di = 0; di < 4; ++di) {
        #pragma unroll
        for (int dj = 0; dj < 4; ++dj) {
            int i = 4 * ti + di, j = 4 * tjj + dj;
            float dist = kn[b * 64 + i] + qn[b * 64 + j] - 2.f * acc[di][dj];
            dist = fmaxf(dist, 0.f) + 64.f * EPSV;
            sc[i][j] = 1.f / (1.f + log1pf(dist));
        }
    }
    __syncthreads();
    if (t < 64) {
        int j = t;
        float m = -1e30f;
        for (int i = 0; i < 64; ++i) m = fmaxf(m, sc[i][j]);
        float ssum = 0.f;
        for (int i = 0; i < 64; ++i) ssum += expf(sc[i][j] - m);
        mx[j] = m; sm[j] = ssum;
    }
    __syncthreads();
    float* Pb = prob + (size_t)b * M * M;
    for (int idx = t; idx < 64 * 64; idx += 256) {
        int j = idx >> 6, i = idx & 63;
        Pb[idx] = expf(sc[i][j] - mx[j]) / sm[j];
    }
}

// ---------------- mixed = prob @ vf  (one block per output row) -----------
__global__ __launch_bounds__(256) void mixed_kernel(
    const float* __restrict__ prob, const float* __restrict__ logV,
    float* __restrict__ mixed)
{
    __shared__ float pr[64];
    const int n = blockIdx.x;        // b*64 + j
    const int b = n >> 6, j = n & 63;
    const int t = threadIdx.x;
    if (t < 64) pr[t] = prob[((size_t)b * 64 + j) * 64 + t];
    __syncthreads();
    const float4* Vb = (const float4*)(logV + (size_t)b * M * DD);
    float4 acc[4];
    #pragma unroll
    for (int u = 0; u < 4; ++u) acc[u] = make_float4(0.f, 0.f, 0.f, 0.f);
    for (int i = 0; i < 64; ++i) {
        float p = pr[i];
        const float4* row = Vb + (size_t)i * (DD / 4);
        #pragma unroll
        for (int u = 0; u < 4; ++u) {
            float4 v = row[t + 256 * u];
            acc[u].x += p * v.x; acc[u].y += p * v.y;
            acc[u].z += p * v.z; acc[u].w += p * v.w;
        }
    }
    float4* Mp = (float4*)(mixed + (size_t)n * DD);
    #pragma unroll
    for (int u = 0; u < 4; ++u) Mp[t + 256 * u] = acc[u];
}

extern "C" void kernel_launch(void* const* d_in, const int* in_sizes, int n_in,
                              void* d_out, int out_size, void* d_ws, size_t ws_size,
                              hipStream_t stream) {
    const float* x  = (const float*)d_in[0];
    const float* Wq = (const float*)d_in[1];
    const float* Wk = (const float*)d_in[2];
    const float* Wv = (const float*)d_in[3];
    float* out = (float*)d_out;
    float* ws  = (float*)d_ws;

    // workspace layout (floats): Q | K | qn | kn | prob ; V/logV lives in d_out,
    // mixed reuses the Q region.
    float* Q    = ws;
    float* K    = Q + (size_t)NMAT * DD;
    float* qn   = K + (size_t)NMAT * DD;
    float* kn   = qn + NMAT;
    float* prob = kn + NMAT;
    float* V    = out;        // logV staged in d_out
    float* mixed = Q;         // overwrites logQ after scores

    transform_kernel<<<NMAT, 256, 0, stream>>>(x, Wq, Wk, Wv, Q, K, V);
    jacobi_kernel<0><<<NMAT, 256, 0, stream>>>(Q, Q, qn);
    jacobi_kernel<0><<<NMAT, 256, 0, stream>>>(K, K, kn);
    jacobi_kernel<0><<<NMAT, 256, 0, stream>>>(V, V, nullptr);
    scores_kernel<<<BS, 256, 0, stream>>>(K, Q, kn, qn, prob);
    mixed_kernel<<<NMAT, 256, 0, stream>>>(prob, V, mixed);
    jacobi_kernel<1><<<NMAT, 256, 0, stream>>>(mixed, out, nullptr);
}

// Round 2
// 14981.148 us; speedup vs baseline: 2.4608x; 2.4608x over previous
//
#include <hip/hip_runtime.h>
#include <math.h>

#define BS 32
#define M 64
#define NMAT 2048      // BS*M
#define DIN 100
#define DOUT 64
#define DD 4096        // DOUT*DOUT
#define EPSV 1e-6f
#define NSWEEP_LOG 7

// ---------------- transform: S = W^T X W for each of q,k,v ----------------
__global__ __launch_bounds__(256) void transform_kernel(
    const float* __restrict__ x,
    const float* __restrict__ Wq, const float* __restrict__ Wk, const float* __restrict__ Wv,
    float* __restrict__ Qo, float* __restrict__ Ko, float* __restrict__ Vo)
{
    __shared__ float Xs[DIN][DIN + 1];      // 100x101
    __shared__ float Ws[DIN][DOUT + 1];     // 100x65
    __shared__ float Ts[DIN][DOUT + 1];     // 100x65
    const int n = blockIdx.x;
    const int t = threadIdx.x;
    const float* Xp = x + (size_t)n * DIN * DIN;
    for (int idx = t; idx < DIN * DIN; idx += 256)
        Xs[idx / DIN][idx % DIN] = Xp[idx];

    const float* Wlist[3] = {Wq, Wk, Wv};
    float* Olist[3] = {Qo, Ko, Vo};
    const int tj = t & 63;   // 0..63
    const int tp = t >> 6;   // 0..3

    for (int w = 0; w < 3; ++w) {
        __syncthreads();     // Xs ready (w=0); Ws/Ts free (w>0)
        const float* W = Wlist[w];
        for (int idx = t; idx < DIN * DOUT; idx += 256)
            Ws[idx / DOUT][idx % DOUT] = W[idx];
        __syncthreads();
        // T = X * W : thread computes T[p][tj] for p = tp + 4*pi
        float acc[25];
        #pragma unroll
        for (int i = 0; i < 25; ++i) acc[i] = 0.f;
        for (int qq = 0; qq < DIN; ++qq) {
            float wv = Ws[qq][tj];
            #pragma unroll
            for (int pi = 0; pi < 25; ++pi)
                acc[pi] += Xs[tp + 4 * pi][qq] * wv;
        }
        #pragma unroll
        for (int pi = 0; pi < 25; ++pi)
            Ts[tp + 4 * pi][tj] = acc[pi];
        __syncthreads();
        // S = W^T * T : thread computes S[i][tj] for i = tp + 4*ii
        float sacc[16];
        #pragma unroll
        for (int i = 0; i < 16; ++i) sacc[i] = 0.f;
        for (int p = 0; p < DIN; ++p) {
            float tv = Ts[p][tj];
            #pragma unroll
            for (int ii = 0; ii < 16; ++ii)
                sacc[ii] += Ws[p][tp + 4 * ii] * tv;
        }
        float* Op = Olist[w] + (size_t)n * DD;
        #pragma unroll
        for (int ii = 0; ii < 16; ++ii)
            Op[(tp + 4 * ii) * DOUT + tj] = sacc[ii];
    }
}

// ---------------- batched symmetric Jacobi eigendecomposition: log --------
// Handles Q (mats 0..2047 -> qn), K (2048..4095 -> kn), V (4096..6143).
// out = U log(|L|+eps) U^T, in place.
__global__ __launch_bounds__(256) void jacobi_log_kernel(
    float* __restrict__ Q, float* __restrict__ K, float* __restrict__ V,
    float* __restrict__ qn, float* __restrict__ kn)
{
    __shared__ float As[DOUT][DOUT + 1];
    __shared__ float Vs[DOUT][DOUT + 1];
    __shared__ float pcs[32], pss[32];
    __shared__ int ppi[32], pqi[32];
    __shared__ float fv[DOUT];
    const int t = threadIdx.x;
    const int mat = blockIdx.x;
    float* base;
    float* nrm = nullptr;
    if (mat < 2048)      { base = Q + (size_t)mat * DD;          nrm = qn + mat; }
    else if (mat < 4096) { base = K + (size_t)(mat - 2048) * DD; nrm = kn + (mat - 2048); }
    else                 { base = V + (size_t)(mat - 4096) * DD; }

    for (int idx = t; idx < DD; idx += 256) {
        int r = idx >> 6, c = idx & 63;
        As[r][c] = base[idx];
        Vs[r][c] = (r == c) ? 1.f : 0.f;
    }
    __syncthreads();

    for (int sw = 0; sw < NSWEEP_LOG; ++sw) {
        for (int rr = 0; rr < 63; ++rr) {
            // 32 disjoint rotation pairs (round-robin / circle ordering)
            if (t < 32) {
                int a, b;
                if (t == 0) { a = 63; b = rr; }
                else { a = (rr + t) % 63; b = (rr - t + 63) % 63; }
                int p = min(a, b), q = max(a, b);
                float app = As[p][p], aqq = As[q][q], apq = As[p][q];
                float c, s;
                if (fabsf(apq) > 1e-30f) {
                    float theta = (aqq - app) / (2.f * apq);
                    float tt = 1.f / (fabsf(theta) + sqrtf(1.f + theta * theta));
                    if (theta < 0.f) tt = -tt;
                    c = rsqrtf(1.f + tt * tt);
                    s = tt * c;
                } else { c = 1.f; s = 0.f; }
                pcs[t] = c; pss[t] = s; ppi[t] = p; pqi[t] = q;
            }
            __syncthreads();
            // A <- J^T A J as 1024 independent 2x2 pair-blocks (in place)
            #pragma unroll
            for (int u = 0; u < 4; ++u) {
                int task = t + 256 * u;
                int kr = task >> 5, kc = task & 31;
                float cr = pcs[kr], sr = pss[kr];
                int pr = ppi[kr], qr = pqi[kr];
                float cc = pcs[kc], sc = pss[kc];
                int pc2 = ppi[kc], qc2 = pqi[kc];
                float a00 = As[pr][pc2], a01 = As[pr][qc2];
                float a10 = As[qr][pc2], a11 = As[qr][qc2];
                // column rotation (A*J)
                float b00 = cc * a00 - sc * a01, b01 = sc * a00 + cc * a01;
                float b10 = cc * a10 - sc * a11, b11 = sc * a10 + cc * a11;
                // row rotation (J^T * )
                As[pr][pc2] = cr * b00 - sr * b10;
                As[pr][qc2] = cr * b01 - sr * b11;
                As[qr][pc2] = sr * b00 + cr * b10;
                As[qr][qc2] = sr * b01 + cr * b11;
            }
            // V <- V J (2048 independent row-tasks, in place)
            #pragma unroll
            for (int u = 0; u < 8; ++u) {
                int task = t + 256 * u;
                int r = task & 63, k = task >> 6;
                float c = pcs[k], s = pss[k];
                int p = ppi[k], q = pqi[k];
                float vp = Vs[r][p], vq = Vs[r][q];
                Vs[r][p] = c * vp - s * vq;
                Vs[r][q] = s * vp + c * vq;
            }
            __syncthreads();
        }
    }

    // eigenvalues on diag; f = log(|lam|+eps)
    if (t < 64) fv[t] = logf(fabsf(As[t][t]) + EPSV);
    __syncthreads();
    if (nrm != nullptr && t == 0) {
        float s = 0.f;
        for (int k = 0; k < 64; ++k) s += fv[k] * fv[k];
        *nrm = s;   // ||log(A)||_F^2 via orthogonality of V
    }
    // B = V * diag(f)  (into As)
    for (int idx = t; idx < DD; idx += 256) {
        int r = idx >> 6, c = idx & 63;
        As[r][c] = Vs[r][c] * fv[c];
    }
    __syncthreads();
    // G = B * V^T
    #pragma unroll
    for (int u = 0; u < 16; ++u) {
        int idx = t + 256 * u;
        int i = idx >> 6, j = idx & 63;
        float acc = 0.f;
        for (int k = 0; k < 64; ++k)
            acc += As[i][k] * Vs[j][k];
        base[idx] = acc;
    }
}

// ---------------- scores + softmax (per batch) ----------------------------
__global__ __launch_bounds__(256) void scores_kernel(
    const float* __restrict__ logK, const float* __restrict__ logQ,
    const float* __restrict__ kn, const float* __restrict__ qn,
    float* __restrict__ prob)
{
    __shared__ float kf_t[64][65];
    __shared__ float qf_t[64][65];
    __shared__ float sc[64][65];
    __shared__ float mx[64], sm[64];
    const int b = blockIdx.x;
    const int t = threadIdx.x;
    const int ti = t >> 4, tjj = t & 15;
    float acc[4][4];
    #pragma unroll
    for (int di = 0; di < 4; ++di)
        #pragma unroll
        for (int dj = 0; dj < 4; ++dj) acc[di][dj] = 0.f;

    const float* Kb = logK + (size_t)b * M * DD;
    const float* Qb = logQ + (size_t)b * M * DD;
    for (int cf = 0; cf < DD; cf += 64) {
        __syncthreads();
        for (int idx = t; idx < 64 * 64; idx += 256) {
            int r = idx >> 6, c = idx & 63;
            kf_t[r][c] = Kb[(size_t)r * DD + cf + c];
            qf_t[r][c] = Qb[(size_t)r * DD + cf + c];
        }
        __syncthreads();
        for (int f = 0; f < 64; ++f) {
            float kv[4], qv[4];
            #pragma unroll
            for (int d = 0; d < 4; ++d) { kv[d] = kf_t[4 * ti + d][f]; qv[d] = qf_t[4 * tjj + d][f]; }
            #pragma unroll
            for (int di = 0; di < 4; ++di)
                #pragma unroll
                for (int dj = 0; dj < 4; ++dj)
                    acc[di][dj] += kv[di] * qv[dj];
        }
    }
    __syncthreads();
    #pragma unroll
    for (int di = 0; di < 4; ++di) {
        #pragma unroll
        for (int dj = 0; dj < 4; ++dj) {
            int i = 4 * ti + di, j = 4 * tjj + dj;
            float dist = kn[b * 64 + i] + qn[b * 64 + j] - 2.f * acc[di][dj];
            dist = fmaxf(dist, 0.f) + 64.f * EPSV;
            sc[i][j] = 1.f / (1.f + log1pf(dist));
        }
    }
    __syncthreads();
    if (t < 64) {
        int j = t;
        float m = -1e30f;
        for (int i = 0; i < 64; ++i) m = fmaxf(m, sc[i][j]);
        float ssum = 0.f;
        for (int i = 0; i < 64; ++i) ssum += expf(sc[i][j] - m);
        mx[j] = m; sm[j] = ssum;
    }
    __syncthreads();
    float* Pb = prob + (size_t)b * M * M;
    for (int idx = t; idx < 64 * 64; idx += 256) {
        int j = idx >> 6, i = idx & 63;
        Pb[idx] = expf(sc[i][j] - mx[j]) / sm[j];
    }
}

// ---------------- mixed = prob @ vf  (one block per output row) -----------
__global__ __launch_bounds__(256) void mixed_kernel(
    const float* __restrict__ prob, const float* __restrict__ logV,
    float* __restrict__ mixed)
{
    __shared__ float pr[64];
    const int n = blockIdx.x;        // b*64 + j
    const int b = n >> 6, j = n & 63;
    const int t = threadIdx.x;
    if (t < 64) pr[t] = prob[((size_t)b * 64 + j) * 64 + t];
    __syncthreads();
    const float4* Vb = (const float4*)(logV + (size_t)b * M * DD);
    float4 acc[4];
    #pragma unroll
    for (int u = 0; u < 4; ++u) acc[u] = make_float4(0.f, 0.f, 0.f, 0.f);
    for (int i = 0; i < 64; ++i) {
        float p = pr[i];
        const float4* row = Vb + (size_t)i * (DD / 4);
        #pragma unroll
        for (int u = 0; u < 4; ++u) {
            float4 v = row[t + 256 * u];
            acc[u].x += p * v.x; acc[u].y += p * v.y;
            acc[u].z += p * v.z; acc[u].w += p * v.w;
        }
    }
    float4* Mp = (float4*)(mixed + (size_t)n * DD);
    #pragma unroll
    for (int u = 0; u < 4; ++u) Mp[t + 256 * u] = acc[u];
}

// ---------------- exp via scaling-and-squaring Taylor (deg 10) ------------
__device__ __forceinline__ void mm64(const float (*A)[DOUT + 1], const float (*B)[DOUT + 1],
                                     float (*C)[DOUT + 1], int t)
{
    const int ti = t >> 4, tj = t & 15;
    float acc[4][4];
    #pragma unroll
    for (int i = 0; i < 4; ++i)
        #pragma unroll
        for (int j = 0; j < 4; ++j) acc[i][j] = 0.f;
    for (int k = 0; k < 64; ++k) {
        float av[4], bv[4];
        #pragma unroll
        for (int d = 0; d < 4; ++d) { av[d] = A[4 * ti + d][k]; bv[d] = B[k][4 * tj + d]; }
        #pragma unroll
        for (int i = 0; i < 4; ++i)
            #pragma unroll
            for (int j = 0; j < 4; ++j)
                acc[i][j] += av[i] * bv[j];
    }
    #pragma unroll
    for (int i = 0; i < 4; ++i)
        #pragma unroll
        for (int j = 0; j < 4; ++j)
            C[4 * ti + i][4 * tj + j] = acc[i][j];
}

__global__ __launch_bounds__(256) void exp_ss_kernel(
    const float* __restrict__ in, float* __restrict__ out)
{
    __shared__ float Bs[DOUT][DOUT + 1];
    __shared__ float Ps[DOUT][DOUT + 1];
    __shared__ float Ts[DOUT][DOUT + 1];
    __shared__ float red[64];
    __shared__ int s_sh;
    __shared__ float scl_sh;
    const int t = threadIdx.x;
    const float* Ap = in + (size_t)blockIdx.x * DD;
    float* Gp = out + (size_t)blockIdx.x * DD;

    for (int idx = t; idx < DD; idx += 256) {
        Bs[idx >> 6][idx & 63] = Ap[idx];
    }
    __syncthreads();
    if (t < 64) {
        float s = 0.f;
        for (int c = 0; c < 64; ++c) s += fabsf(Bs[t][c]);
        red[t] = s;
    }
    __syncthreads();
    if (t == 0) {
        float mx = 0.f;
        for (int k = 0; k < 64; ++k) mx = fmaxf(mx, red[k]);
        int s = 0;
        while (mx > 0.5f && s < 30) { mx *= 0.5f; ++s; }
        s_sh = s;
        scl_sh = ldexpf(1.f, -s);
    }
    __syncthreads();
    const int nsq = s_sh;
    const float scl = scl_sh;
    // scale B in place; init P = I + B/10
    for (int idx = t; idx < DD; idx += 256) {
        int r = idx >> 6, c = idx & 63;
        float b = Bs[r][c] * scl;
        Bs[r][c] = b;
        Ps[r][c] = b * 0.1f + ((r == c) ? 1.f : 0.f);
    }
    __syncthreads();
    // Horner: P <- I + (B*P)/k for k = 9..1
    #pragma unroll 1
    for (int k = 9; k >= 1; --k) {
        mm64(Bs, Ps, Ts, t);
        __syncthreads();
        float rk = 1.f / (float)k;
        for (int idx = t; idx < DD; idx += 256) {
            int r = idx >> 6, c = idx & 63;
            Ps[r][c] = Ts[r][c] * rk + ((r == c) ? 1.f : 0.f);
        }
        __syncthreads();
    }
    // squarings
    #pragma unroll 1
    for (int j = 0; j < nsq; ++j) {
        mm64(Ps, Ps, Ts, t);
        __syncthreads();
        for (int idx = t; idx < DD; idx += 256)
            Ps[idx >> 6][idx & 63] = Ts[idx >> 6][idx & 63];
        __syncthreads();
    }
    for (int idx = t; idx < DD; idx += 256)
        Gp[idx] = Ps[idx >> 6][idx & 63];
}

extern "C" void kernel_launch(void* const* d_in, const int* in_sizes, int n_in,
                              void* d_out, int out_size, void* d_ws, size_t ws_size,
                              hipStream_t stream) {
    const float* x  = (const float*)d_in[0];
    const float* Wq = (const float*)d_in[1];
    const float* Wk = (const float*)d_in[2];
    const float* Wv = (const float*)d_in[3];
    float* out = (float*)d_out;
    float* ws  = (float*)d_ws;

    // workspace layout (floats): Q | K | qn | kn | prob ; V/logV lives in d_out,
    // mixed reuses the Q region.
    float* Q    = ws;
    float* K    = Q + (size_t)NMAT * DD;
    float* qn   = K + (size_t)NMAT * DD;
    float* kn   = qn + NMAT;
    float* prob = kn + NMAT;
    float* V    = out;        // logV staged in d_out
    float* mixed = Q;         // overwrites logQ after scores

    transform_kernel<<<NMAT, 256, 0, stream>>>(x, Wq, Wk, Wv, Q, K, V);
    jacobi_log_kernel<<<3 * NMAT, 256, 0, stream>>>(Q, K, V, qn, kn);
    scores_kernel<<<BS, 256, 0, stream>>>(K, Q, kn, qn, prob);
    mixed_kernel<<<NMAT, 256, 0, stream>>>(prob, V, mixed);
    exp_ss_kernel<<<NMAT, 256, 0, stream>>>(mixed, out);
}

// Round 3
// 5873.185 us; speedup vs baseline: 6.2768x; 2.5508x over previous
//
#include <hip/hip_runtime.h>
#include <math.h>

#define BS 32
#define M 64
#define NMAT 2048      // BS*M
#define DIN 100
#define DOUT 64
#define DD 4096        // DOUT*DOUT
#define EPSV 1e-6f
#define NSWEEP_1S 8

__device__ __forceinline__ float bperm(int addr, float v) {
    return __int_as_float(__builtin_amdgcn_ds_bpermute(addr, __float_as_int(v)));
}

// ---------------- transform: S = W^T X W for each of q,k,v ----------------
__global__ __launch_bounds__(256) void transform_kernel(
    const float* __restrict__ x,
    const float* __restrict__ Wq, const float* __restrict__ Wk, const float* __restrict__ Wv,
    float* __restrict__ Qo, float* __restrict__ Ko, float* __restrict__ Vo)
{
    __shared__ float Xs[DIN][DIN + 1];      // 100x101
    __shared__ float Ws[DIN][DOUT + 1];     // 100x65
    __shared__ float Ts[DIN][DOUT + 1];     // 100x65
    const int n = blockIdx.x;
    const int t = threadIdx.x;
    const float* Xp = x + (size_t)n * DIN * DIN;
    for (int idx = t; idx < DIN * DIN; idx += 256)
        Xs[idx / DIN][idx % DIN] = Xp[idx];

    const float* Wlist[3] = {Wq, Wk, Wv};
    float* Olist[3] = {Qo, Ko, Vo};
    const int tj = t & 63;   // 0..63
    const int tp = t >> 6;   // 0..3

    for (int w = 0; w < 3; ++w) {
        __syncthreads();     // Xs ready (w=0); Ws/Ts free (w>0)
        const float* W = Wlist[w];
        for (int idx = t; idx < DIN * DOUT; idx += 256)
            Ws[idx / DOUT][idx % DOUT] = W[idx];
        __syncthreads();
        // T = X * W : thread computes T[p][tj] for p = tp + 4*pi
        float acc[25];
        #pragma unroll
        for (int i = 0; i < 25; ++i) acc[i] = 0.f;
        for (int qq = 0; qq < DIN; ++qq) {
            float wv = Ws[qq][tj];
            #pragma unroll
            for (int pi = 0; pi < 25; ++pi)
                acc[pi] += Xs[tp + 4 * pi][qq] * wv;
        }
        #pragma unroll
        for (int pi = 0; pi < 25; ++pi)
            Ts[tp + 4 * pi][tj] = acc[pi];
        __syncthreads();
        // S = W^T * T : thread computes S[i][tj] for i = tp + 4*ii
        float sacc[16];
        #pragma unroll
        for (int i = 0; i < 16; ++i) sacc[i] = 0.f;
        for (int p = 0; p < DIN; ++p) {
            float tv = Ts[p][tj];
            #pragma unroll
            for (int ii = 0; ii < 16; ++ii)
                sacc[ii] += Ws[p][tp + 4 * ii] * tv;
        }
        float* Op = Olist[w] + (size_t)n * DD;
        #pragma unroll
        for (int ii = 0; ii < 16; ++ii)
            Op[(tp + 4 * ii) * DOUT + tj] = sacc[ii];
    }
}

// ---------------- one-sided Jacobi (SVD) — one wave per matrix ------------
// For SPD A: iterate A <- A*J until columns orthogonal. Final columns
// g_l = sigma_l * u_l with sigma = eigenvalue. Writes G in place, plus
// w_l = log(sigma_l + eps)/sigma_l^2 and (for Q,K) sum_l log(...)^2.
__global__ __launch_bounds__(256) void jacobi1s_kernel(
    float* __restrict__ Q, float* __restrict__ K, float* __restrict__ V,
    float* __restrict__ wbuf, float* __restrict__ qn, float* __restrict__ kn)
{
    const int lane = threadIdx.x & 63;
    const int wid  = threadIdx.x >> 6;
    const int mat  = blockIdx.x * 4 + wid;
    float* base;
    float* nrm = nullptr;
    if (mat < NMAT)          { base = Q + (size_t)mat * DD;            nrm = qn + mat; }
    else if (mat < 2 * NMAT) { base = K + (size_t)(mat - NMAT) * DD;   nrm = kn + (mat - NMAT); }
    else                     { base = V + (size_t)(mat - 2 * NMAT) * DD; }

    // Lane `lane` owns column `lane`. A is symmetric -> column == row, so load
    // row `lane` with float4 (contiguous per lane).
    float g[64];
    {
        const float4* rp = (const float4*)(base + (size_t)lane * DOUT);
        #pragma unroll
        for (int i = 0; i < 16; ++i) {
            float4 v = rp[i];
            g[4 * i + 0] = v.x; g[4 * i + 1] = v.y;
            g[4 * i + 2] = v.z; g[4 * i + 3] = v.w;
        }
    }

    for (int sw = 0; sw < NSWEEP_1S; ++sw) {
        for (int rr = 0; rr < 63; ++rr) {
            // round-robin tournament pairing; closed-form partner
            int partner;
            if (lane == 63)      partner = rr;
            else if (lane == rr) partner = 63;
            else                 partner = (2 * rr - lane + 63) % 63;
            const int paddr = partner << 2;

            // self norm^2 (fresh each round: robust, cheap)
            float dself = 0.f;
            #pragma unroll
            for (int i = 0; i < 64; ++i) dself = fmaf(g[i], g[i], dself);
            float dpart = bperm(paddr, dself);

            // cross dot <g_self, g_partner>  (identical value on both lanes)
            float dot = 0.f;
            #pragma unroll
            for (int i = 0; i < 64; ++i) dot = fmaf(g[i], bperm(paddr, g[i]), dot);

            // rotation params for ordered pair (p,q) = (min,max)
            const bool isp = lane < partner;
            float dpp = isp ? dself : dpart;
            float dqq = isp ? dpart : dself;
            float c = 1.f, s = 0.f;
            if (dot * dot > 1e-16f * dpp * dqq) {
                float theta = (dqq - dpp) / (2.f * dot);
                float t = 1.f / (fabsf(theta) + sqrtf(1.f + theta * theta));
                if (theta < 0.f) t = -t;
                c = rsqrtf(1.f + t * t);
                s = t * c;
            }
            const float sgn = isp ? -s : s;
            // g_p' = c g_p - s g_q ; g_q' = s g_p + c g_q
            // (wave-lockstep: bperm(g[i]) always reads pre-update value, since
            //  the update consuming it is data-dependent on the bperm result)
            #pragma unroll
            for (int i = 0; i < 64; ++i)
                g[i] = fmaf(c, g[i], sgn * bperm(paddr, g[i]));
        }
    }

    // epilogue: sigma, f = log(sigma+eps), w = f/sigma^2
    float d = 0.f;
    #pragma unroll
    for (int i = 0; i < 64; ++i) d = fmaf(g[i], g[i], d);
    float sigma = sqrtf(d);
    float f = logf(sigma + EPSV);
    float w = f / d;

    // write G back (lane's column scattered across rows -> coalesced stores)
    #pragma unroll
    for (int i = 0; i < 64; ++i) base[i * DOUT + lane] = g[i];
    wbuf[(size_t)mat * 64 + lane] = w;

    if (nrm != nullptr) {
        float nf = f * f;
        #pragma unroll
        for (int off = 32; off >= 1; off >>= 1) nf += __shfl_xor(nf, off, 64);
        if (lane == 0) *nrm = nf;
    }
}

// ---------------- reconstruction: logA = G diag(w) G^T, in place ----------
__global__ __launch_bounds__(256) void recon_log_kernel(
    float* __restrict__ Q, float* __restrict__ K, float* __restrict__ V,
    const float* __restrict__ wbuf)
{
    __shared__ float Gs[64][65];
    __shared__ float Bs[64][65];
    __shared__ float ws[64];
    const int t = threadIdx.x;
    const int mat = blockIdx.x;
    float* base;
    if (mat < NMAT)          base = Q + (size_t)mat * DD;
    else if (mat < 2 * NMAT) base = K + (size_t)(mat - NMAT) * DD;
    else                     base = V + (size_t)(mat - 2 * NMAT) * DD;

    for (int idx = t; idx < DD; idx += 256)
        Gs[idx >> 6][idx & 63] = base[idx];
    if (t < 64) ws[t] = wbuf[(size_t)mat * 64 + t];
    __syncthreads();
    for (int idx = t; idx < DD; idx += 256) {
        int r = idx >> 6, c = idx & 63;
        Bs[r][c] = Gs[r][c] * ws[c];
    }
    __syncthreads();
    // out[i][j] = sum_k Bs[i][k] * Gs[j][k] ; 4x4 register tile per thread
    const int ti = t >> 4, tj = t & 15;
    float acc[4][4];
    #pragma unroll
    for (int i = 0; i < 4; ++i)
        #pragma unroll
        for (int j = 0; j < 4; ++j) acc[i][j] = 0.f;
    for (int k = 0; k < 64; ++k) {
        float av[4], bv[4];
        #pragma unroll
        for (int d = 0; d < 4; ++d) { av[d] = Bs[4 * ti + d][k]; bv[d] = Gs[4 * tj + d][k]; }
        #pragma unroll
        for (int i = 0; i < 4; ++i)
            #pragma unroll
            for (int j = 0; j < 4; ++j)
                acc[i][j] += av[i] * bv[j];
    }
    #pragma unroll
    for (int i = 0; i < 4; ++i) {
        float4 v;
        v.x = acc[i][0]; v.y = acc[i][1]; v.z = acc[i][2]; v.w = acc[i][3];
        *(float4*)(base + (4 * ti + i) * DOUT + 4 * tj) = v;
    }
}

// ---------------- scores + softmax (per batch) ----------------------------
__global__ __launch_bounds__(256) void scores_kernel(
    const float* __restrict__ logK, const float* __restrict__ logQ,
    const float* __restrict__ kn, const float* __restrict__ qn,
    float* __restrict__ prob)
{
    __shared__ float kf_t[64][65];
    __shared__ float qf_t[64][65];
    __shared__ float sc[64][65];
    __shared__ float mx[64], sm[64];
    const int b = blockIdx.x;
    const int t = threadIdx.x;
    const int ti = t >> 4, tjj = t & 15;
    float acc[4][4];
    #pragma unroll
    for (int di = 0; di < 4; ++di)
        #pragma unroll
        for (int dj = 0; dj < 4; ++dj) acc[di][dj] = 0.f;

    const float* Kb = logK + (size_t)b * M * DD;
    const float* Qb = logQ + (size_t)b * M * DD;
    for (int cf = 0; cf < DD; cf += 64) {
        __syncthreads();
        for (int idx = t; idx < 64 * 64; idx += 256) {
            int r = idx >> 6, c = idx & 63;
            kf_t[r][c] = Kb[(size_t)r * DD + cf + c];
            qf_t[r][c] = Qb[(size_t)r * DD + cf + c];
        }
        __syncthreads();
        for (int f = 0; f < 64; ++f) {
            float kv[4], qv[4];
            #pragma unroll
            for (int d = 0; d < 4; ++d) { kv[d] = kf_t[4 * ti + d][f]; qv[d] = qf_t[4 * tjj + d][f]; }
            #pragma unroll
            for (int di = 0; di < 4; ++di)
                #pragma unroll
                for (int dj = 0; dj < 4; ++dj)
                    acc[di][dj] += kv[di] * qv[dj];
        }
    }
    __syncthreads();
    #pragma unroll
    for (int di = 0; di < 4; ++di) {
        #pragma unroll
        for (int dj = 0; dj < 4; ++dj) {
            int i = 4 * ti + di, j = 4 * tjj + dj;
            float dist = kn[b * 64 + i] + qn[b * 64 + j] - 2.f * acc[di][dj];
            dist = fmaxf(dist, 0.f) + 64.f * EPSV;
            sc[i][j] = 1.f / (1.f + log1pf(dist));
        }
    }
    __syncthreads();
    if (t < 64) {
        int j = t;
        float m = -1e30f;
        for (int i = 0; i < 64; ++i) m = fmaxf(m, sc[i][j]);
        float ssum = 0.f;
        for (int i = 0; i < 64; ++i) ssum += expf(sc[i][j] - m);
        mx[j] = m; sm[j] = ssum;
    }
    __syncthreads();
    float* Pb = prob + (size_t)b * M * M;
    for (int idx = t; idx < 64 * 64; idx += 256) {
        int j = idx >> 6, i = idx & 63;
        Pb[idx] = expf(sc[i][j] - mx[j]) / sm[j];
    }
}

// ---------------- mixed = prob @ vf  (one block per output row) -----------
__global__ __launch_bounds__(256) void mixed_kernel(
    const float* __restrict__ prob, const float* __restrict__ logV,
    float* __restrict__ mixed)
{
    __shared__ float pr[64];
    const int n = blockIdx.x;        // b*64 + j
    const int b = n >> 6, j = n & 63;
    const int t = threadIdx.x;
    if (t < 64) pr[t] = prob[((size_t)b * 64 + j) * 64 + t];
    __syncthreads();
    const float4* Vb = (const float4*)(logV + (size_t)b * M * DD);
    float4 acc[4];
    #pragma unroll
    for (int u = 0; u < 4; ++u) acc[u] = make_float4(0.f, 0.f, 0.f, 0.f);
    for (int i = 0; i < 64; ++i) {
        float p = pr[i];
        const float4* row = Vb + (size_t)i * (DD / 4);
        #pragma unroll
        for (int u = 0; u < 4; ++u) {
            float4 v = row[t + 256 * u];
            acc[u].x += p * v.x; acc[u].y += p * v.y;
            acc[u].z += p * v.z; acc[u].w += p * v.w;
        }
    }
    float4* Mp = (float4*)(mixed + (size_t)n * DD);
    #pragma unroll
    for (int u = 0; u < 4; ++u) Mp[t + 256 * u] = acc[u];
}

// ---------------- exp via scaling-and-squaring Taylor (deg 10) ------------
__device__ __forceinline__ void mm64(const float (*A)[DOUT + 1], const float (*B)[DOUT + 1],
                                     float (*C)[DOUT + 1], int t)
{
    const int ti = t >> 4, tj = t & 15;
    float acc[4][4];
    #pragma unroll
    for (int i = 0; i < 4; ++i)
        #pragma unroll
        for (int j = 0; j < 4; ++j) acc[i][j] = 0.f;
    for (int k = 0; k < 64; ++k) {
        float av[4], bv[4];
        #pragma unroll
        for (int d = 0; d < 4; ++d) { av[d] = A[4 * ti + d][k]; bv[d] = B[k][4 * tj + d]; }
        #pragma unroll
        for (int i = 0; i < 4; ++i)
            #pragma unroll
            for (int j = 0; j < 4; ++j)
                acc[i][j] += av[i] * bv[j];
    }
    #pragma unroll
    for (int i = 0; i < 4; ++i)
        #pragma unroll
        for (int j = 0; j < 4; ++j)
            C[4 * ti + i][4 * tj + j] = acc[i][j];
}

__global__ __launch_bounds__(256) void exp_ss_kernel(
    const float* __restrict__ in, float* __restrict__ out)
{
    __shared__ float Bs[DOUT][DOUT + 1];
    __shared__ float Ps[DOUT][DOUT + 1];
    __shared__ float Ts[DOUT][DOUT + 1];
    __shared__ float red[64];
    __shared__ int s_sh;
    __shared__ float scl_sh;
    const int t = threadIdx.x;
    const float* Ap = in + (size_t)blockIdx.x * DD;
    float* Gp = out + (size_t)blockIdx.x * DD;

    for (int idx = t; idx < DD; idx += 256) {
        Bs[idx >> 6][idx & 63] = Ap[idx];
    }
    __syncthreads();
    if (t < 64) {
        float s = 0.f;
        for (int c = 0; c < 64; ++c) s += fabsf(Bs[t][c]);
        red[t] = s;
    }
    __syncthreads();
    if (t == 0) {
        float mx = 0.f;
        for (int k = 0; k < 64; ++k) mx = fmaxf(mx, red[k]);
        int s = 0;
        while (mx > 0.5f && s < 30) { mx *= 0.5f; ++s; }
        s_sh = s;
        scl_sh = ldexpf(1.f, -s);
    }
    __syncthreads();
    const int nsq = s_sh;
    const float scl = scl_sh;
    // scale B in place; init P = I + B/10
    for (int idx = t; idx < DD; idx += 256) {
        int r = idx >> 6, c = idx & 63;
        float b = Bs[r][c] * scl;
        Bs[r][c] = b;
        Ps[r][c] = b * 0.1f + ((r == c) ? 1.f : 0.f);
    }
    __syncthreads();
    // Horner: P <- I + (B*P)/k for k = 9..1
    #pragma unroll 1
    for (int k = 9; k >= 1; --k) {
        mm64(Bs, Ps, Ts, t);
        __syncthreads();
        float rk = 1.f / (float)k;
        for (int idx = t; idx < DD; idx += 256) {
            int r = idx >> 6, c = idx & 63;
            Ps[r][c] = Ts[r][c] * rk + ((r == c) ? 1.f : 0.f);
        }
        __syncthreads();
    }
    // squarings
    #pragma unroll 1
    for (int j = 0; j < nsq; ++j) {
        mm64(Ps, Ps, Ts, t);
        __syncthreads();
        for (int idx = t; idx < DD; idx += 256)
            Ps[idx >> 6][idx & 63] = Ts[idx >> 6][idx & 63];
        __syncthreads();
    }
    for (int idx = t; idx < DD; idx += 256)
        Gp[idx] = Ps[idx >> 6][idx & 63];
}

extern "C" void kernel_launch(void* const* d_in, const int* in_sizes, int n_in,
                              void* d_out, int out_size, void* d_ws, size_t ws_size,
                              hipStream_t stream) {
    const float* x  = (const float*)d_in[0];
    const float* Wq = (const float*)d_in[1];
    const float* Wk = (const float*)d_in[2];
    const float* Wv = (const float*)d_in[3];
    float* out = (float*)d_out;
    float* ws  = (float*)d_ws;

    // ws layout (floats): Q | K | qn | kn | prob | wbuf ; V/logV in d_out.
    float* Q    = ws;
    float* K    = Q + (size_t)NMAT * DD;
    float* qn   = K + (size_t)NMAT * DD;
    float* kn   = qn + NMAT;
    float* prob = kn + NMAT;
    float* wbuf = prob + (size_t)BS * M * M;
    float* V    = out;        // logV staged in d_out
    float* mixed = Q;         // overwrites logQ after scores

    transform_kernel<<<NMAT, 256, 0, stream>>>(x, Wq, Wk, Wv, Q, K, V);
    jacobi1s_kernel<<<(3 * NMAT) / 4, 256, 0, stream>>>(Q, K, V, wbuf, qn, kn);
    recon_log_kernel<<<3 * NMAT, 256, 0, stream>>>(Q, K, V, wbuf);
    scores_kernel<<<BS, 256, 0, stream>>>(K, Q, kn, qn, prob);
    mixed_kernel<<<NMAT, 256, 0, stream>>>(prob, V, mixed);
    exp_ss_kernel<<<NMAT, 256, 0, stream>>>(mixed, out);
}

// Round 4
// 3513.793 us; speedup vs baseline: 10.4915x; 1.6715x over previous
//
#include <hip/hip_runtime.h>
#include <math.h>

#define BS 32
#define M 64
#define NMAT 2048      // BS*M
#define DIN 100
#define DOUT 64
#define DD 4096        // DOUT*DOUT
#define EPSV 1e-6f
#define NSWEEP_1S 8

__device__ __forceinline__ float bperm(int addr, float v) {
    return __int_as_float(__builtin_amdgcn_ds_bpermute(addr, __float_as_int(v)));
}

// ---------------- transform: S = W^T X W for each of q,k,v ----------------
__global__ __launch_bounds__(256) void transform_kernel(
    const float* __restrict__ x,
    const float* __restrict__ Wq, const float* __restrict__ Wk, const float* __restrict__ Wv,
    float* __restrict__ Qo, float* __restrict__ Ko, float* __restrict__ Vo)
{
    __shared__ float Xs[DIN][DIN + 1];      // 100x101
    __shared__ float Ws[DIN][DOUT + 1];     // 100x65
    __shared__ float Ts[DIN][DOUT + 1];     // 100x65
    const int n = blockIdx.x;
    const int t = threadIdx.x;
    const float* Xp = x + (size_t)n * DIN * DIN;
    for (int idx = t; idx < DIN * DIN; idx += 256)
        Xs[idx / DIN][idx % DIN] = Xp[idx];

    const float* Wlist[3] = {Wq, Wk, Wv};
    float* Olist[3] = {Qo, Ko, Vo};
    const int tj = t & 63;   // 0..63
    const int tp = t >> 6;   // 0..3

    for (int w = 0; w < 3; ++w) {
        __syncthreads();     // Xs ready (w=0); Ws/Ts free (w>0)
        const float* W = Wlist[w];
        for (int idx = t; idx < DIN * DOUT; idx += 256)
            Ws[idx / DOUT][idx % DOUT] = W[idx];
        __syncthreads();
        // T = X * W : thread computes T[p][tj] for p = tp + 4*pi
        float acc[25];
        #pragma unroll
        for (int i = 0; i < 25; ++i) acc[i] = 0.f;
        for (int qq = 0; qq < DIN; ++qq) {
            float wv = Ws[qq][tj];
            #pragma unroll
            for (int pi = 0; pi < 25; ++pi)
                acc[pi] += Xs[tp + 4 * pi][qq] * wv;
        }
        #pragma unroll
        for (int pi = 0; pi < 25; ++pi)
            Ts[tp + 4 * pi][tj] = acc[pi];
        __syncthreads();
        // S = W^T * T : thread computes S[i][tj] for i = tp + 4*ii
        float sacc[16];
        #pragma unroll
        for (int i = 0; i < 16; ++i) sacc[i] = 0.f;
        for (int p = 0; p < DIN; ++p) {
            float tv = Ts[p][tj];
            #pragma unroll
            for (int ii = 0; ii < 16; ++ii)
                sacc[ii] += Ws[p][tp + 4 * ii] * tv;
        }
        float* Op = Olist[w] + (size_t)n * DD;
        #pragma unroll
        for (int ii = 0; ii < 16; ++ii)
            Op[(tp + 4 * ii) * DOUT + tj] = sacc[ii];
    }
}

// ---------------- one-sided Jacobi (SVD) — one wave per matrix ------------
// For SPD A: iterate A <- A*J until columns orthogonal. Final columns
// g_l = sigma_l * u_l with sigma = eigenvalue. Writes G in place, plus
// w_l = log(sigma_l + eps)/sigma_l^2 and (for Q,K) sum_l log(...)^2.
// XOR pair ordering: round rr pairs lane with lane^(rr+1) — every unordered
// pair exactly once per sweep. Partner column cached in registers (one
// bperm pass per round); column norms maintained incrementally via the
// exact Jacobi diagonal update nself' = nself -/+ t*dot.
__global__ __launch_bounds__(256) void jacobi1s_kernel(
    float* __restrict__ Q, float* __restrict__ K, float* __restrict__ V,
    float* __restrict__ wbuf, float* __restrict__ qn, float* __restrict__ kn)
{
    const int lane = threadIdx.x & 63;
    const int wid  = threadIdx.x >> 6;
    const int mat  = blockIdx.x * 4 + wid;
    float* base;
    float* nrm = nullptr;
    if (mat < NMAT)          { base = Q + (size_t)mat * DD;            nrm = qn + mat; }
    else if (mat < 2 * NMAT) { base = K + (size_t)(mat - NMAT) * DD;   nrm = kn + (mat - NMAT); }
    else                     { base = V + (size_t)(mat - 2 * NMAT) * DD; }

    // Lane `lane` owns column `lane`. A is symmetric -> column == row, so load
    // row `lane` with float4 (contiguous per lane).
    float g[64];
    {
        const float4* rp = (const float4*)(base + (size_t)lane * DOUT);
        #pragma unroll
        for (int i = 0; i < 16; ++i) {
            float4 v = rp[i];
            g[4 * i + 0] = v.x; g[4 * i + 1] = v.y;
            g[4 * i + 2] = v.z; g[4 * i + 3] = v.w;
        }
    }

    for (int sw = 0; sw < NSWEEP_1S; ++sw) {
        // exact norm at sweep start (kills incremental drift)
        float nself;
        {
            float n0 = 0.f, n1 = 0.f, n2 = 0.f, n3 = 0.f;
            #pragma unroll
            for (int i = 0; i < 64; i += 4) {
                n0 = fmaf(g[i + 0], g[i + 0], n0);
                n1 = fmaf(g[i + 1], g[i + 1], n1);
                n2 = fmaf(g[i + 2], g[i + 2], n2);
                n3 = fmaf(g[i + 3], g[i + 3], n3);
            }
            nself = (n0 + n1) + (n2 + n3);
        }
        for (int rr = 0; rr < 63; ++rr) {
            const int partner = lane ^ (rr + 1);
            const int paddr = partner << 2;
            const float dpart = bperm(paddr, nself);

            // fetch partner column once; dot via 4 split chains
            float gp[64];
            #pragma unroll
            for (int i = 0; i < 64; ++i) gp[i] = bperm(paddr, g[i]);
            float d0 = 0.f, d1 = 0.f, d2 = 0.f, d3 = 0.f;
            #pragma unroll
            for (int i = 0; i < 64; i += 4) {
                d0 = fmaf(g[i + 0], gp[i + 0], d0);
                d1 = fmaf(g[i + 1], gp[i + 1], d1);
                d2 = fmaf(g[i + 2], gp[i + 2], d2);
                d3 = fmaf(g[i + 3], gp[i + 3], d3);
            }
            const float dot = (d0 + d1) + (d2 + d3);

            // rotation params for ordered pair (p,q) = (min,max)
            const bool isp = lane < partner;
            const float dpp = isp ? nself : dpart;
            const float dqq = isp ? dpart : nself;
            float c = 1.f, s = 0.f, tt = 0.f;
            if (dot * dot > 1e-16f * dpp * dqq) {
                float theta = (dqq - dpp) / (2.f * dot);
                tt = 1.f / (fabsf(theta) + sqrtf(1.f + theta * theta));
                if (theta < 0.f) tt = -tt;
                c = rsqrtf(1.f + tt * tt);
                s = tt * c;
            }
            const float sgn = isp ? -s : s;
            // g_p' = c g_p - s g_q ; g_q' = s g_p + c g_q
            #pragma unroll
            for (int i = 0; i < 64; ++i)
                g[i] = fmaf(c, g[i], sgn * gp[i]);
            // exact diagonal update of the Gram matrix under this rotation
            nself = fmaf(isp ? -tt : tt, dot, nself);
        }
    }

    // epilogue: sigma, f = log(sigma+eps), w = f/sigma^2 (exact recompute)
    float d;
    {
        float n0 = 0.f, n1 = 0.f, n2 = 0.f, n3 = 0.f;
        #pragma unroll
        for (int i = 0; i < 64; i += 4) {
            n0 = fmaf(g[i + 0], g[i + 0], n0);
            n1 = fmaf(g[i + 1], g[i + 1], n1);
            n2 = fmaf(g[i + 2], g[i + 2], n2);
            n3 = fmaf(g[i + 3], g[i + 3], n3);
        }
        d = (n0 + n1) + (n2 + n3);
    }
    float sigma = sqrtf(d);
    float f = logf(sigma + EPSV);
    float w = f / d;

    // write G back (lane's column scattered across rows -> coalesced stores)
    #pragma unroll
    for (int i = 0; i < 64; ++i) base[i * DOUT + lane] = g[i];
    wbuf[(size_t)mat * 64 + lane] = w;

    if (nrm != nullptr) {
        float nf = f * f;
        #pragma unroll
        for (int off = 32; off >= 1; off >>= 1) nf += __shfl_xor(nf, off, 64);
        if (lane == 0) *nrm = nf;
    }
}

// ---------------- reconstruction: logA = G diag(w) G^T, in place ----------
__global__ __launch_bounds__(256) void recon_log_kernel(
    float* __restrict__ Q, float* __restrict__ K, float* __restrict__ V,
    const float* __restrict__ wbuf)
{
    __shared__ float Gs[64][65];
    __shared__ float Bs[64][65];
    __shared__ float ws[64];
    const int t = threadIdx.x;
    const int mat = blockIdx.x;
    float* base;
    if (mat < NMAT)          base = Q + (size_t)mat * DD;
    else if (mat < 2 * NMAT) base = K + (size_t)(mat - NMAT) * DD;
    else                     base = V + (size_t)(mat - 2 * NMAT) * DD;

    for (int idx = t; idx < DD; idx += 256)
        Gs[idx >> 6][idx & 63] = base[idx];
    if (t < 64) ws[t] = wbuf[(size_t)mat * 64 + t];
    __syncthreads();
    for (int idx = t; idx < DD; idx += 256) {
        int r = idx >> 6, c = idx & 63;
        Bs[r][c] = Gs[r][c] * ws[c];
    }
    __syncthreads();
    // out[i][j] = sum_k Bs[i][k] * Gs[j][k] ; 4x4 register tile per thread
    const int ti = t >> 4, tj = t & 15;
    float acc[4][4];
    #pragma unroll
    for (int i = 0; i < 4; ++i)
        #pragma unroll
        for (int j = 0; j < 4; ++j) acc[i][j] = 0.f;
    for (int k = 0; k < 64; ++k) {
        float av[4], bv[4];
        #pragma unroll
        for (int d = 0; d < 4; ++d) { av[d] = Bs[4 * ti + d][k]; bv[d] = Gs[4 * tj + d][k]; }
        #pragma unroll
        for (int i = 0; i < 4; ++i)
            #pragma unroll
            for (int j = 0; j < 4; ++j)
                acc[i][j] += av[i] * bv[j];
    }
    #pragma unroll
    for (int i = 0; i < 4; ++i) {
        float4 v;
        v.x = acc[i][0]; v.y = acc[i][1]; v.z = acc[i][2]; v.w = acc[i][3];
        *(float4*)(base + (4 * ti + i) * DOUT + 4 * tj) = v;
    }
}

// ---------------- scores + softmax (per batch) ----------------------------
__global__ __launch_bounds__(256) void scores_kernel(
    const float* __restrict__ logK, const float* __restrict__ logQ,
    const float* __restrict__ kn, const float* __restrict__ qn,
    float* __restrict__ prob)
{
    __shared__ float kf_t[64][65];
    __shared__ float qf_t[64][65];
    __shared__ float sc[64][65];
    __shared__ float mx[64], sm[64];
    const int b = blockIdx.x;
    const int t = threadIdx.x;
    const int ti = t >> 4, tjj = t & 15;
    float acc[4][4];
    #pragma unroll
    for (int di = 0; di < 4; ++di)
        #pragma unroll
        for (int dj = 0; dj < 4; ++dj) acc[di][dj] = 0.f;

    const float* Kb = logK + (size_t)b * M * DD;
    const float* Qb = logQ + (size_t)b * M * DD;
    for (int cf = 0; cf < DD; cf += 64) {
        __syncthreads();
        for (int idx = t; idx < 64 * 64; idx += 256) {
            int r = idx >> 6, c = idx & 63;
            kf_t[r][c] = Kb[(size_t)r * DD + cf + c];
            qf_t[r][c] = Qb[(size_t)r * DD + cf + c];
        }
        __syncthreads();
        for (int f = 0; f < 64; ++f) {
            float kv[4], qv[4];
            #pragma unroll
            for (int d = 0; d < 4; ++d) { kv[d] = kf_t[4 * ti + d][f]; qv[d] = qf_t[4 * tjj + d][f]; }
            #pragma unroll
            for (int di = 0; di < 4; ++di)
                #pragma unroll
                for (int dj = 0; dj < 4; ++dj)
                    acc[di][dj] += kv[di] * qv[dj];
        }
    }
    __syncthreads();
    #pragma unroll
    for (int di = 0; di < 4; ++di) {
        #pragma unroll
        for (int dj = 0; dj < 4; ++dj) {
            int i = 4 * ti + di, j = 4 * tjj + dj;
            float dist = kn[b * 64 + i] + qn[b * 64 + j] - 2.f * acc[di][dj];
            dist = fmaxf(dist, 0.f) + 64.f * EPSV;
            sc[i][j] = 1.f / (1.f + log1pf(dist));
        }
    }
    __syncthreads();
    if (t < 64) {
        int j = t;
        float m = -1e30f;
        for (int i = 0; i < 64; ++i) m = fmaxf(m, sc[i][j]);
        float ssum = 0.f;
        for (int i = 0; i < 64; ++i) ssum += expf(sc[i][j] - m);
        mx[j] = m; sm[j] = ssum;
    }
    __syncthreads();
    float* Pb = prob + (size_t)b * M * M;
    for (int idx = t; idx < 64 * 64; idx += 256) {
        int j = idx >> 6, i = idx & 63;
        Pb[idx] = expf(sc[i][j] - mx[j]) / sm[j];
    }
}

// ---------------- mixed = prob @ vf  (one block per output row) -----------
__global__ __launch_bounds__(256) void mixed_kernel(
    const float* __restrict__ prob, const float* __restrict__ logV,
    float* __restrict__ mixed)
{
    __shared__ float pr[64];
    const int n = blockIdx.x;        // b*64 + j
    const int b = n >> 6, j = n & 63;
    const int t = threadIdx.x;
    if (t < 64) pr[t] = prob[((size_t)b * 64 + j) * 64 + t];
    __syncthreads();
    const float4* Vb = (const float4*)(logV + (size_t)b * M * DD);
    float4 acc[4];
    #pragma unroll
    for (int u = 0; u < 4; ++u) acc[u] = make_float4(0.f, 0.f, 0.f, 0.f);
    for (int i = 0; i < 64; ++i) {
        float p = pr[i];
        const float4* row = Vb + (size_t)i * (DD / 4);
        #pragma unroll
        for (int u = 0; u < 4; ++u) {
            float4 v = row[t + 256 * u];
            acc[u].x += p * v.x; acc[u].y += p * v.y;
            acc[u].z += p * v.z; acc[u].w += p * v.w;
        }
    }
    float4* Mp = (float4*)(mixed + (size_t)n * DD);
    #pragma unroll
    for (int u = 0; u < 4; ++u) Mp[t + 256 * u] = acc[u];
}

// ---------------- exp via scaling-and-squaring Taylor (deg 10) ------------
__device__ __forceinline__ void mm64(const float (*A)[DOUT + 1], const float (*B)[DOUT + 1],
                                     float (*C)[DOUT + 1], int t)
{
    const int ti = t >> 4, tj = t & 15;
    float acc[4][4];
    #pragma unroll
    for (int i = 0; i < 4; ++i)
        #pragma unroll
        for (int j = 0; j < 4; ++j) acc[i][j] = 0.f;
    for (int k = 0; k < 64; ++k) {
        float av[4], bv[4];
        #pragma unroll
        for (int d = 0; d < 4; ++d) { av[d] = A[4 * ti + d][k]; bv[d] = B[k][4 * tj + d]; }
        #pragma unroll
        for (int i = 0; i < 4; ++i)
            #pragma unroll
            for (int j = 0; j < 4; ++j)
                acc[i][j] += av[i] * bv[j];
    }
    #pragma unroll
    for (int i = 0; i < 4; ++i)
        #pragma unroll
        for (int j = 0; j < 4; ++j)
            C[4 * ti + i][4 * tj + j] = acc[i][j];
}

__global__ __launch_bounds__(256) void exp_ss_kernel(
    const float* __restrict__ in, float* __restrict__ out)
{
    __shared__ float Bs[DOUT][DOUT + 1];
    __shared__ float Ps[DOUT][DOUT + 1];
    __shared__ float Ts[DOUT][DOUT + 1];
    __shared__ float red[64];
    __shared__ int s_sh;
    __shared__ float scl_sh;
    const int t = threadIdx.x;
    const float* Ap = in + (size_t)blockIdx.x * DD;
    float* Gp = out + (size_t)blockIdx.x * DD;

    for (int idx = t; idx < DD; idx += 256) {
        Bs[idx >> 6][idx & 63] = Ap[idx];
    }
    __syncthreads();
    if (t < 64) {
        float s = 0.f;
        for (int c = 0; c < 64; ++c) s += fabsf(Bs[t][c]);
        red[t] = s;
    }
    __syncthreads();
    if (t == 0) {
        float mx = 0.f;
        for (int k = 0; k < 64; ++k) mx = fmaxf(mx, red[k]);
        int s = 0;
        while (mx > 0.5f && s < 30) { mx *= 0.5f; ++s; }
        s_sh = s;
        scl_sh = ldexpf(1.f, -s);
    }
    __syncthreads();
    const int nsq = s_sh;
    const float scl = scl_sh;
    // scale B in place; init P = I + B/10
    for (int idx = t; idx < DD; idx += 256) {
        int r = idx >> 6, c = idx & 63;
        float b = Bs[r][c] * scl;
        Bs[r][c] = b;
        Ps[r][c] = b * 0.1f + ((r == c) ? 1.f : 0.f);
    }
    __syncthreads();
    // Horner: P <- I + (B*P)/k for k = 9..1
    #pragma unroll 1
    for (int k = 9; k >= 1; --k) {
        mm64(Bs, Ps, Ts, t);
        __syncthreads();
        float rk = 1.f / (float)k;
        for (int idx = t; idx < DD; idx += 256) {
            int r = idx >> 6, c = idx & 63;
            Ps[r][c] = Ts[r][c] * rk + ((r == c) ? 1.f : 0.f);
        }
        __syncthreads();
    }
    // squarings
    #pragma unroll 1
    for (int j = 0; j < nsq; ++j) {
        mm64(Ps, Ps, Ts, t);
        __syncthreads();
        for (int idx = t; idx < DD; idx += 256)
            Ps[idx >> 6][idx & 63] = Ts[idx >> 6][idx & 63];
        __syncthreads();
    }
    for (int idx = t; idx < DD; idx += 256)
        Gp[idx] = Ps[idx >> 6][idx & 63];
}

extern "C" void kernel_launch(void* const* d_in, const int* in_sizes, int n_in,
                              void* d_out, int out_size, void* d_ws, size_t ws_size,
                              hipStream_t stream) {
    const float* x  = (const float*)d_in[0];
    const float* Wq = (const float*)d_in[1];
    const float* Wk = (const float*)d_in[2];
    const float* Wv = (const float*)d_in[3];
    float* out = (float*)d_out;
    float* ws  = (float*)d_ws;

    // ws layout (floats): Q | K | qn | kn | prob | wbuf ; V/logV in d_out.
    float* Q    = ws;
    float* K    = Q + (size_t)NMAT * DD;
    float* qn   = K + (size_t)NMAT * DD;
    float* kn   = qn + NMAT;
    float* prob = kn + NMAT;
    float* wbuf = prob + (size_t)BS * M * M;
    float* V    = out;        // logV staged in d_out
    float* mixed = Q;         // overwrites logQ after scores

    transform_kernel<<<NMAT, 256, 0, stream>>>(x, Wq, Wk, Wv, Q, K, V);
    jacobi1s_kernel<<<(3 * NMAT) / 4, 256, 0, stream>>>(Q, K, V, wbuf, qn, kn);
    recon_log_kernel<<<3 * NMAT, 256, 0, stream>>>(Q, K, V, wbuf);
    scores_kernel<<<BS, 256, 0, stream>>>(K, Q, kn, qn, prob);
    mixed_kernel<<<NMAT, 256, 0, stream>>>(prob, V, mixed);
    exp_ss_kernel<<<NMAT, 256, 0, stream>>>(mixed, out);
}